// Round 4
// baseline (372.613 us; speedup 1.0000x reference)
//
#include <hip/hip_runtime.h>
#include <math.h>

// Problem constants
#define B_    128
#define T_    2048
#define DIN   128
#define HID_  132
#define DOUT  64

// Tiling
#define TC    128            // time-steps per fused block
#define NCC   (T_ / TC)      // 16 chunks
#define AS    168            // act row stride (f16): 336B, 16B-aligned, 2-way banks (free)
#define WSTR  72             // wt row stride (f16): 144B, 16B-aligned, 2-way banks (free)
#define MAXU  5              // max 16B staging units per thread (1152/256 -> 5)

typedef _Float16 half8   __attribute__((ext_vector_type(8)));
typedef _Float16 half4v  __attribute__((ext_vector_type(4)));
typedef float    float4v __attribute__((ext_vector_type(4)));

// ---------------------------------------------------------------------------
// Kernel 1: blocks [0,32): weight->f16 transpose prep (runs in round 0).
//           blocks [32, 32+2048): per-chunk column max of P.
// ---------------------------------------------------------------------------
__global__ __launch_bounds__(256) void prep_chunkmax_kernel(
    const float* __restrict__ P,
    const float* __restrict__ W1, const float* __restrict__ b1,
    const float* __restrict__ W2, const float* __restrict__ b2,
    const float* __restrict__ W3, const float* __restrict__ b3,
    const float* __restrict__ W4, const float* __restrict__ b4,
    float* __restrict__ cmax,
    _Float16* __restrict__ WT1, _Float16* __restrict__ WT2,
    _Float16* __restrict__ WT3, _Float16* __restrict__ WT4,
    float* __restrict__ bpad) {
    const int bid = blockIdx.x;
    const int tid = threadIdx.x;
    if (bid >= 32) {
        // ---- chunk max: 256 threads = (d 0..127) x (half 0..1) ----
        __shared__ float part[256];
        const int cb = bid - 32;
        const int b = cb >> 4, c = cb & 15;
        const int d = tid & 127, h = tid >> 7;
        const float* p = P + ((size_t)(b * T_ + c * TC + h * 64)) * DIN + d;
        float m = -INFINITY;
#pragma unroll 16
        for (int t = 0; t < 64; ++t) m = fmaxf(m, p[(size_t)t * DIN]);
        part[tid] = m;
        __syncthreads();
        if (h == 0)
            cmax[((size_t)b * NCC + c) * DIN + d] = fmaxf(part[d], part[128 + d]);
    } else {
        // ---- weight prep: 8 slice-blocks per layer, coalesced row reads ----
        const int l = bid >> 3, slice = bid & 7;
        const float *W, *bs; _Float16* dst; int K, N, KP, R, NB;
        if (l == 0)      { W = W1; bs = b1; dst = WT1; K = 128; N = 132; KP = 128; R = 144; NB = 132; }
        else if (l == 1) { W = W2; bs = b2; dst = WT2; K = 132; N = 132; KP = 160; R = 144; NB = 132; }
        else if (l == 2) { W = W3; bs = b3; dst = WT3; K = 132; N = 132; KP = 160; R = 144; NB = 132; }
        else             { W = W4; bs = b4; dst = WT4; K = 132; N = 64;  KP = 160; R = 64;  NB = 64;  }
        for (int k = slice; k < KP; k += 8) {
            for (int n = tid; n < R; n += 256) {
                float v = (k < K && n < N) ? W[(size_t)k * N + n] : 0.f;
                dst[(size_t)n * KP + k] = (_Float16)v;
            }
        }
        if (slice == 0)
            for (int i = tid; i < 144; i += 256)
                bpad[l * 144 + i] = (i < NB) ? bs[i] : 0.f;
    }
}

// ---------------------------------------------------------------------------
// Prefetch helper: issue global 16B loads for one weight chunk into regs.
// rows, ktot, kb, sh are wave-uniform.
// ---------------------------------------------------------------------------
__device__ __forceinline__ void issue_chunk(const _Float16* __restrict__ src,
                                            int ktot, int rows, int kb, int sh,
                                            int tid, uint4 (&R)[MAXU]) {
    const int total = rows << sh;
#pragma unroll
    for (int i = 0; i < MAXU; ++i) {
        const int u = tid + 256 * i;
        if (u < total) {
            const int n = u >> sh, s = u & ((1 << sh) - 1);
            R[i] = *(const uint4*)(src + (size_t)n * ktot + kb + s * 8);
        }
    }
}

// ---------------------------------------------------------------------------
// One MLP layer via 16x16x32 f16 MFMA, swapped operands (D = W x act -> D^T).
// r2 mapping: wave w owns rows [32w,32w+32) (2 strips), all NT n-tiles.
// Weight chunks are software-pipelined: R holds this layer's kb=0 on entry;
// each iteration writes R->LDS then issues the NEXT chunk (incl. next layer).
// ---------------------------------------------------------------------------
template <int NT, int KTOT, bool LAST, int NROWS_NEXT, int KT_NEXT>
__device__ __forceinline__ void mlp_layer(const _Float16* __restrict__ WTg,
                                          const float* __restrict__ bp,
                                          _Float16* act, _Float16* wt,
                                          float* __restrict__ outg, int tid,
                                          const _Float16* __restrict__ WTnext,
                                          uint4 (&R)[MAXU]) {
    const int wave = tid >> 6, lane = tid & 63;
    const int quad = lane >> 4, l16 = lane & 15;
    float4v C0[NT], C1[NT];
#pragma unroll
    for (int nt = 0; nt < NT; ++nt) { C0[nt] = (float4v)0.0f; C1[nt] = (float4v)0.0f; }

    const int r0 = 32 * wave + l16;
    int kb = 0;
    while (kb < KTOT) {
        const int kc = (KTOT - kb < 64) ? (KTOT - kb) : 64;   // 64 or 32
        const int sh = (kc == 64) ? 3 : 2;
        const int total = (NT * 16) << sh;
        __syncthreads();   // prior wt readers done; prior act writes visible
        // R -> LDS
#pragma unroll
        for (int i = 0; i < MAXU; ++i) {
            const int u = tid + 256 * i;
            if (u < total) {
                const int n = u >> sh, s = u & ((1 << sh) - 1);
                *(uint4*)(wt + n * WSTR + s * 8) = R[i];
            }
        }
        // issue next chunk while this one computes
        const int nkb = kb + kc;
        if (nkb < KTOT) {
            const int nkc = (KTOT - nkb < 64) ? (KTOT - nkb) : 64;
            issue_chunk(WTg, KTOT, NT * 16, nkb, (nkc == 64) ? 3 : 2, tid, R);
        } else if (!LAST) {
            issue_chunk(WTnext, KT_NEXT, NROWS_NEXT, 0, 3, tid, R);
        }
        __syncthreads();
        for (int kt = 0; kt < kc; kt += 32) {
            const int ko = kb + kt + quad * 8;
            half8 a0 = *(const half8*)(act + (size_t)r0 * AS + ko);
            half8 a1 = *(const half8*)(act + (size_t)(r0 + 16) * AS + ko);
#pragma unroll
            for (int nt = 0; nt < NT; ++nt) {
                half8 w = *(const half8*)(wt + (nt * 16 + l16) * WSTR + kt + quad * 8);
                C0[nt] = __builtin_amdgcn_mfma_f32_16x16x32_f16(w, a0, C0[nt], 0, 0, 0);
                C1[nt] = __builtin_amdgcn_mfma_f32_16x16x32_f16(w, a1, C1[nt], 0, 0, 0);
            }
        }
        kb = nkb;
    }
    __syncthreads();   // all act reads done before in-place overwrite
#pragma unroll
    for (int s = 0; s < 2; ++s) {
        const int m = 32 * wave + 16 * s + l16;
#pragma unroll
        for (int nt = 0; nt < NT; ++nt) {
            const int n0 = nt * 16 + quad * 4;
            float4v c = s ? C1[nt] : C0[nt];
            float4v bv = *(const float4v*)(bp + n0);
            if (LAST) {
                float4v o;
#pragma unroll
                for (int r = 0; r < 4; ++r)
                    o[r] = 1.f / (1.f + __expf(-5.f * (c[r] + bv[r])));
                *(float4v*)(outg + (size_t)m * DOUT + n0) = o;
            } else {
                half4v hv;
#pragma unroll
                for (int r = 0; r < 4; ++r)
                    hv[r] = (_Float16)fmaxf(c[r] + bv[r], 0.f);
                *(half4v*)(act + (size_t)m * AS + n0) = hv;
            }
        }
    }
    // next layer's first __syncthreads() orders these writes vs. its reads
}

// ---------------------------------------------------------------------------
// Fused kernel: tail-suffix from cmax + reverse cummax -> 4 MFMA layers
// ---------------------------------------------------------------------------
__global__ __launch_bounds__(256, 2) void fused_kernel(
    const float* __restrict__ P, const float* __restrict__ cmax,
    const _Float16* __restrict__ WT1, const _Float16* __restrict__ WT2,
    const _Float16* __restrict__ WT3, const _Float16* __restrict__ WT4,
    const float* __restrict__ bpad, float* __restrict__ Out) {
    __shared__ _Float16 act[TC * AS];     // 43008 B
    __shared__ _Float16 wt[144 * WSTR];   // 20736 B  (total 63744 <= 64 KiB, 2 blocks/CU)

    const int bid = blockIdx.x;
    const int b = bid / NCC, c = bid % NCC;
    const int tid = threadIdx.x;

    uint4 R[MAXU];
    // issue layer-1 chunk-0 weight loads NOW; they fly under the cummax phase
    issue_chunk(WT1, 128, 144, 0, 3, tid, R);

    {   // zero K-pad cols [144,160) once (read by layers 2-4)
        const int m = tid >> 1, s2 = tid & 1;
        uint4 z{0, 0, 0, 0};
        *(uint4*)(act + (size_t)m * AS + 144 + s2 * 8) = z;
    }
    {   // reverse cummax, 2 threads per column; hf==1 seeds from later-chunk maxima
        const int d = tid & 127, hf = tid >> 7;
        float run = -INFINITY;
        if (hf == 1)
            for (int j = c + 1; j < NCC; ++j)
                run = fmaxf(run, cmax[((size_t)b * NCC + j) * DIN + d]);
        const float* p = P + ((size_t)(b * T_ + c * TC + hf * 64)) * DIN + d;
#pragma unroll 16
        for (int t = 63; t >= 0; --t) {
            run = fmaxf(run, p[(size_t)t * DIN]);
            act[(size_t)(hf * 64 + t) * AS + d] = (_Float16)run;
        }
        __syncthreads();
        // fold suffix of later half into first half: all 256 threads, b128 RMW
        const int cg = tid & 15, tg = tid >> 4;          // col-group, t-group
        half8 mx = *(const half8*)(act + (size_t)64 * AS + 8 * cg);
#pragma unroll
        for (int i = 0; i < 4; ++i) {
            const int t = tg * 4 + i;
            half8 v = *(const half8*)(act + (size_t)t * AS + 8 * cg);
            half8 r;
#pragma unroll
            for (int j = 0; j < 8; ++j) r[j] = (v[j] > mx[j]) ? v[j] : mx[j];
            *(half8*)(act + (size_t)t * AS + 8 * cg) = r;
        }
        // mlp_layer's first two __syncthreads() order these writes vs. reads
    }

    float* outg = Out + (size_t)(b * T_ + c * TC) * DOUT;
    mlp_layer<9, 128, false, 144, 160>(WT1, bpad,       act, wt, nullptr, tid, WT2, R);
    mlp_layer<9, 160, false, 144, 160>(WT2, bpad + 144, act, wt, nullptr, tid, WT3, R);
    mlp_layer<9, 160, false,  64, 160>(WT3, bpad + 288, act, wt, nullptr, tid, WT4, R);
    mlp_layer<4, 160, true,    0,   0>(WT4, bpad + 432, act, wt, outg,    tid, nullptr, R);
}

// ---------------------------------------------------------------------------
extern "C" void kernel_launch(void* const* d_in, const int* in_sizes, int n_in,
                              void* d_out, int out_size, void* d_ws, size_t ws_size,
                              hipStream_t stream) {
    const float* P  = (const float*)d_in[0];
    const float* W1 = (const float*)d_in[1];
    const float* b1 = (const float*)d_in[2];
    const float* W2 = (const float*)d_in[3];
    const float* b2 = (const float*)d_in[4];
    const float* W3 = (const float*)d_in[5];
    const float* b3 = (const float*)d_in[6];
    const float* W4 = (const float*)d_in[7];
    const float* b4 = (const float*)d_in[8];
    float* out = (float*)d_out;

    // ws layout
    char* ws = (char*)d_ws;
    float*    cmax = (float*)ws;                          // 128*16*128*4 = 1 MiB
    _Float16* WT1  = (_Float16*)(ws + (1 << 20));         // 144*128 f16
    _Float16* WT2  = WT1 + 144 * 128;                     // 144*160
    _Float16* WT3  = WT2 + 144 * 160;                     // 144*160
    _Float16* WT4  = WT3 + 144 * 160;                     // 64*160
    float*    bpad = (float*)(WT4 + 64 * 160);            // 4*144 f32 (16B-aligned)

    prep_chunkmax_kernel<<<B_ * NCC + 32, 256, 0, stream>>>(
        P, W1, b1, W2, b2, W3, b3, W4, b4, cmax, WT1, WT2, WT3, WT4, bpad);
    fused_kernel<<<B_ * NCC, 256, 0, stream>>>(P, cmax, WT1, WT2, WT3, WT4,
                                               bpad, out);
}

// Round 5
// 302.221 us; speedup vs baseline: 1.2329x; 1.2329x over previous
//
#include <hip/hip_runtime.h>
#include <math.h>

// Problem constants
#define B_    128
#define T_    2048
#define DIN   128
#define HID_  132
#define DOUT  64

// Tiling
#define TC    128            // time-steps per fused block
#define NCC   (T_ / TC)      // 16 chunks
#define AS    168            // act row stride (f16): 336B, 16B-aligned, conflict-benign
#define WBUF  9216           // one wt buffer: 144 rows x 64 f16 = 18432 B

typedef _Float16 half8   __attribute__((ext_vector_type(8)));
typedef _Float16 half4v  __attribute__((ext_vector_type(4)));
typedef float    float4v __attribute__((ext_vector_type(4)));

__device__ __forceinline__ float4v max4(float4v a, float4v b) {
    float4v r;
#pragma unroll
    for (int i = 0; i < 4; ++i) r[i] = fmaxf(a[i], b[i]);
    return r;
}

// ---------------------------------------------------------------------------
// global -> LDS direct DMA, 16B/lane, contiguous 1KB per wave-instruction.
// bytes must be a multiple of 1024. Instr i of wave w covers [w*1024 + i*4096).
// ---------------------------------------------------------------------------
__device__ __forceinline__ void dma_chunk(const _Float16* __restrict__ src,
                                          _Float16* dst, int bytes, int tid) {
    const int w = tid >> 6, lane = tid & 63;
    for (int off = w * 1024; off < bytes; off += 4096) {
        const char* g = (const char*)src + off + lane * 16;
        char*       l = (char*)dst + off + lane * 16;
        __builtin_amdgcn_global_load_lds(
            (const __attribute__((address_space(1))) unsigned int*)g,
            (__attribute__((address_space(3))) unsigned int*)l, 16, 0, 0);
    }
}

// ---------------------------------------------------------------------------
// Kernel 1: blocks [0,32): weight prep into DMA-swizzled layout.
//           blocks [32, 32+2048): per-chunk column max of P (float4 loads).
// Swizzle (per layer, rows R, padded K = KP): element (k, n) lives at
//   ci=k/64, kr=k%64, kc=min(64,KP-64ci), g=kr/8, j=kr%8, h=g/4, q=g%4
//   off = ci*R*64 + (n/16)*16*kc + h*512 + q*128 + (n%16)*8 + j
// so one 64-k chunk is lane-contiguous in exactly MFMA fragment order.
// ---------------------------------------------------------------------------
__global__ __launch_bounds__(256) void prep_chunkmax_kernel(
    const float* __restrict__ P,
    const float* __restrict__ W1, const float* __restrict__ b1,
    const float* __restrict__ W2, const float* __restrict__ b2,
    const float* __restrict__ W3, const float* __restrict__ b3,
    const float* __restrict__ W4, const float* __restrict__ b4,
    float* __restrict__ cmax,
    _Float16* __restrict__ SW1, _Float16* __restrict__ SW2,
    _Float16* __restrict__ SW3, _Float16* __restrict__ SW4,
    float* __restrict__ bpad) {
    const int bid = blockIdx.x;
    const int tid = threadIdx.x;
    if (bid >= 32) {
        // ---- chunk max: (c4 0..31 covering d) x (sg 0..7 t-segments) ----
        __shared__ float4v smax1[256];
        const int cb = bid - 32;
        const int b = cb >> 4, c = cb & 15;
        const int c4 = tid & 31, sg = tid >> 5;
        const float* p = P + ((size_t)(b * T_ + c * TC + sg * 16)) * DIN + c4 * 4;
        float4v m = {-INFINITY, -INFINITY, -INFINITY, -INFINITY};
#pragma unroll
        for (int i = 0; i < 16; ++i)
            m = max4(m, *(const float4v*)(p + (size_t)i * DIN));
        smax1[sg * 32 + c4] = m;
        __syncthreads();
        if (tid < 32) {
            float4v r = smax1[tid];
#pragma unroll
            for (int s = 1; s < 8; ++s) r = max4(r, smax1[s * 32 + tid]);
            *(float4v*)(cmax + ((size_t)b * NCC + c) * DIN + tid * 4) = r;
        }
    } else {
        // ---- weight prep: 8 slice-blocks per layer, coalesced row reads ----
        const int l = bid >> 3, slice = bid & 7;
        const float *W, *bs; _Float16* dst; int K, N, KP, R, NB;
        if (l == 0)      { W = W1; bs = b1; dst = SW1; K = 128; N = 132; KP = 128; R = 144; NB = 132; }
        else if (l == 1) { W = W2; bs = b2; dst = SW2; K = 132; N = 132; KP = 160; R = 144; NB = 132; }
        else if (l == 2) { W = W3; bs = b3; dst = SW3; K = 132; N = 132; KP = 160; R = 144; NB = 132; }
        else             { W = W4; bs = b4; dst = SW4; K = 132; N = 64;  KP = 160; R = 64;  NB = 64;  }
        for (int k = slice; k < KP; k += 8) {
            const int ci = k >> 6, kr = k & 63;
            const int kc = (KP - (ci << 6) < 64) ? 32 : 64;
            const int g = kr >> 3, j = kr & 7, h = g >> 2, q = g & 3;
            for (int n = tid; n < R; n += 256) {
                float v = (k < K && n < N) ? W[(size_t)k * N + n] : 0.f;
                size_t off = (size_t)ci * R * 64 + (size_t)(n >> 4) * 16 * kc +
                             h * 512 + q * 128 + (n & 15) * 8 + j;
                dst[off] = (_Float16)v;
            }
        }
        if (slice == 0)
            for (int i = tid; i < 144; i += 256)
                bpad[l * 144 + i] = (i < NB) ? bs[i] : 0.f;
    }
}

// ---------------------------------------------------------------------------
// One MLP layer via 16x16x32 f16 MFMA, swapped operands (D = W x act -> D^T).
// Wave w owns rows [32w,32w+32) (2 strips), all NT n-tiles. Weight chunks are
// double-buffered via global_load_lds: chunk i+1's DMA issues AFTER the
// barrier gating compute(i), so its latency hides under compute(i).
// PAR = buffer index of this layer's chunk 0; NEXTB = next layer chunk0 bytes.
// ---------------------------------------------------------------------------
template <int NT, int KTOT, bool LAST, int PAR, int NEXTB>
__device__ __forceinline__ void mlp_layer(const _Float16* __restrict__ Wsw,
                                          const float* __restrict__ bp,
                                          _Float16* act, _Float16* wtA, _Float16* wtB,
                                          float* __restrict__ outg, int tid,
                                          const _Float16* __restrict__ Wnext) {
    const int wave = tid >> 6, lane = tid & 63;
    const int quad = lane >> 4, l16 = lane & 15;
    constexpr int NCH = (KTOT + 63) / 64;
    float4v C0[NT], C1[NT];
#pragma unroll
    for (int nt = 0; nt < NT; ++nt) { C0[nt] = (float4v)0.0f; C1[nt] = (float4v)0.0f; }

    const int r0 = 32 * wave + l16;
#pragma unroll
    for (int ci = 0; ci < NCH; ++ci) {
        const int kb = ci * 64;
        const int kc = (KTOT - kb < 64) ? 32 : 64;
        _Float16* cur = ((PAR + ci) & 1) ? wtB : wtA;
        _Float16* nxt = ((PAR + ci) & 1) ? wtA : wtB;
        __syncthreads();   // drains chunk-ci DMA (in flight since last barrier)
        if (ci + 1 < NCH) {
            const int nb = (KTOT - (kb + 64) < 64) ? NT * 16 * 32 * 2 : NT * 16 * 64 * 2;
            dma_chunk(Wsw + (size_t)(kb + 64) * (NT * 16), nxt, nb, tid);
        } else if (!LAST) {
            dma_chunk(Wnext, nxt, NEXTB, tid);
        }
#pragma unroll
        for (int kt = 0; kt < kc; kt += 32) {
            const int ko = kb + kt + quad * 8;
            half8 a0 = *(const half8*)(act + (size_t)r0 * AS + ko);
            half8 a1 = *(const half8*)(act + (size_t)(r0 + 16) * AS + ko);
            const _Float16* wb = cur + (kt >> 5) * 512 + quad * 128 + l16 * 8;
#pragma unroll
            for (int nt = 0; nt < NT; ++nt) {
                half8 w = *(const half8*)(wb + nt * 16 * kc);
                C0[nt] = __builtin_amdgcn_mfma_f32_16x16x32_f16(w, a0, C0[nt], 0, 0, 0);
                C1[nt] = __builtin_amdgcn_mfma_f32_16x16x32_f16(w, a1, C1[nt], 0, 0, 0);
            }
        }
    }
    if (!LAST) __syncthreads();   // all act reads done before in-place overwrite
#pragma unroll
    for (int s = 0; s < 2; ++s) {
        const int m = 32 * wave + 16 * s + l16;
#pragma unroll
        for (int nt = 0; nt < NT; ++nt) {
            const int n0 = nt * 16 + quad * 4;
            float4v c = s ? C1[nt] : C0[nt];
            float4v bv = *(const float4v*)(bp + n0);
            if (LAST) {
                float4v o;
#pragma unroll
                for (int r = 0; r < 4; ++r)
                    o[r] = 1.f / (1.f + __expf(-5.f * (c[r] + bv[r])));
                *(float4v*)(outg + (size_t)m * DOUT + n0) = o;
            } else {
                half4v hv;
#pragma unroll
                for (int r = 0; r < 4; ++r)
                    hv[r] = (_Float16)fmaxf(c[r] + bv[r], 0.f);
                *(half4v*)(act + (size_t)m * AS + n0) = hv;
            }
        }
    }
    // next layer's first __syncthreads() orders these writes vs. its reads
}

// ---------------------------------------------------------------------------
// Fused kernel: reverse cummax (8 parallel segments + merge) -> 4 MFMA layers
// ---------------------------------------------------------------------------
__global__ __launch_bounds__(256, 2) void fused_kernel(
    const float* __restrict__ P, const float* __restrict__ cmax,
    const _Float16* __restrict__ SW1, const _Float16* __restrict__ SW2,
    const _Float16* __restrict__ SW3, const _Float16* __restrict__ SW4,
    const float* __restrict__ bpad, float* __restrict__ Out) {
    __shared__ __align__(16) _Float16 act[TC * AS];      // 43008 B
    __shared__ __align__(16) _Float16 wtbuf[2 * WBUF];   // 36864 B (total 79872 -> 2 blk/CU)
    _Float16* wtA = wtbuf;
    _Float16* wtB = wtbuf + WBUF;

    const int bid = blockIdx.x;
    const int b = bid / NCC, c = bid % NCC;
    const int tid = threadIdx.x;

    // layer-1 chunk-0 weight DMA flies under the whole cummax phase (-> wtA)
    dma_chunk(SW1, wtA, 144 * 64 * 2, tid);

    {   // zero K-pad cols [144,160) (read as A-operand by layers 2-4)
        const int m = tid >> 1, s2 = tid & 1;
        uint4 z{0, 0, 0, 0};
        *(uint4*)(act + (size_t)m * AS + 144 + s2 * 8) = z;
    }
    {   // reverse cummax: 8 parallel t-segments of 16, float4 columns
        float4v* smax = (float4v*)wtB;   // alias: wtB idle until chunk1 DMA
        const int c4 = tid & 31, sg = tid >> 5;
        const float* p = P + ((size_t)(b * T_ + c * TC + sg * 16)) * DIN + c4 * 4;
        float4v run = {-INFINITY, -INFINITY, -INFINITY, -INFINITY};
#pragma unroll
        for (int i = 15; i >= 0; --i) {
            run = max4(run, *(const float4v*)(p + (size_t)i * DIN));
            half4v h;
#pragma unroll
            for (int j = 0; j < 4; ++j) h[j] = (_Float16)run[j];
            *(half4v*)(act + (size_t)(sg * 16 + i) * AS + c4 * 4) = h;
        }
        smax[sg * 32 + c4] = run;
        __syncthreads();
        // tail = max over later chunks + later segments; fold into own segment
        float4v tail = {-INFINITY, -INFINITY, -INFINITY, -INFINITY};
        for (int j = c + 1; j < NCC; ++j)
            tail = max4(tail, *(const float4v*)(cmax + ((size_t)b * NCC + j) * DIN + c4 * 4));
        for (int s = sg + 1; s < 8; ++s) tail = max4(tail, smax[s * 32 + c4]);
        half4v tl;
#pragma unroll
        for (int j = 0; j < 4; ++j) tl[j] = (_Float16)tail[j];
#pragma unroll
        for (int i = 0; i < 16; ++i) {
            _Float16* a = act + (size_t)(sg * 16 + i) * AS + c4 * 4;
            half4v v = *(half4v*)a;
            half4v r;
#pragma unroll
            for (int j = 0; j < 4; ++j) r[j] = (v[j] > tl[j]) ? v[j] : tl[j];
            *(half4v*)a = r;
        }
        // mlp_layer's first __syncthreads() orders these vs. fragment reads
    }

    float* outg = Out + (size_t)(b * T_ + c * TC) * DOUT;
    mlp_layer<9, 128, false, 0, 18432>(SW1, bpad,       act, wtA, wtB, nullptr, tid, SW2);
    mlp_layer<9, 160, false, 0, 18432>(SW2, bpad + 144, act, wtA, wtB, nullptr, tid, SW3);
    mlp_layer<9, 160, false, 1, 8192 >(SW3, bpad + 288, act, wtA, wtB, nullptr, tid, SW4);
    mlp_layer<4, 160, true,  0, 0    >(SW4, bpad + 432, act, wtA, wtB, outg,    tid, nullptr);
}

// ---------------------------------------------------------------------------
extern "C" void kernel_launch(void* const* d_in, const int* in_sizes, int n_in,
                              void* d_out, int out_size, void* d_ws, size_t ws_size,
                              hipStream_t stream) {
    const float* P  = (const float*)d_in[0];
    const float* W1 = (const float*)d_in[1];
    const float* b1 = (const float*)d_in[2];
    const float* W2 = (const float*)d_in[3];
    const float* b2 = (const float*)d_in[4];
    const float* W3 = (const float*)d_in[5];
    const float* b3 = (const float*)d_in[6];
    const float* W4 = (const float*)d_in[7];
    const float* b4 = (const float*)d_in[8];
    float* out = (float*)d_out;

    // ws layout
    char* ws = (char*)d_ws;
    float*    cmax = (float*)ws;                          // 1 MiB
    _Float16* SW1  = (_Float16*)(ws + (1 << 20));         // 144*128 f16 (swizzled)
    _Float16* SW2  = SW1 + 144 * 128;                     // 144*160
    _Float16* SW3  = SW2 + 144 * 160;                     // 144*160
    _Float16* SW4  = SW3 + 144 * 160;                     // 64*160
    float*    bpad = (float*)(SW4 + 64 * 160);            // 4*144 f32

    prep_chunkmax_kernel<<<B_ * NCC + 32, 256, 0, stream>>>(
        P, W1, b1, W2, b2, W3, b3, W4, b4, cmax, SW1, SW2, SW3, SW4, bpad);
    fused_kernel<<<B_ * NCC, 256, 0, stream>>>(P, cmax, SW1, SW2, SW3, SW4,
                                               bpad, out);
}